// Round 3
// baseline (315.334 us; speedup 1.0000x reference)
//
#include <hip/hip_runtime.h>

#define B_ 2
#define S_ 2048
#define D_ 1024
#define H_ 16
#define HD_ 64

typedef unsigned short u16;
typedef short bf16x8 __attribute__((ext_vector_type(8)));
typedef float f32x4 __attribute__((ext_vector_type(4)));

union FragU { bf16x8 v; u16 u[8]; uint2 d2[2]; };

__device__ __forceinline__ u16 f2bf(float f) {
  unsigned int x = __builtin_bit_cast(unsigned int, f);
  x += 0x7fffu + ((x >> 16) & 1u);   // round-to-nearest-even
  return (u16)(x >> 16);
}

#define SWZ(row, cb) ((cb) ^ (((row) & 7) << 4))

// ---------------------------------------------------------------------------
// prep: W[z][h][k][n] f32  ->  WT[z][h*64+n][k] bf16   (transpose + convert)
// 48 blocks (z,h) x 256 thr; lanes n-consecutive -> coalesced 256B gathers.
// ---------------------------------------------------------------------------
__global__ __launch_bounds__(256) void prep_kernel(
    const float* __restrict__ Wq, const float* __restrict__ Wk,
    const float* __restrict__ Wv, u16* __restrict__ WT)
{
  const int blk = blockIdx.x;
  const int z = blk >> 4, h = blk & 15;
  const float* src = ((z == 0) ? Wq : (z == 1) ? Wk : Wv) + (size_t)h * D_ * HD_;
  u16* dst = WT + (size_t)z * D_ * D_ + (size_t)h * HD_ * D_;   // [64 n][1024 k]
  const int tid = threadIdx.x;
  const int n = tid & 63, kh = tid >> 6;         // kh: k-quarter 0..3
  for (int k8 = 0; k8 < 32; ++k8) {
    const int kbase = kh * 256 + k8 * 8;
    union { u16 u[8]; uint4 q; } pk;
    #pragma unroll
    for (int m = 0; m < 8; ++m)
      pk.u[m] = f2bf(src[(size_t)(kbase + m) * HD_ + n]);
    *(uint4*)(dst + (size_t)n * D_ + kbase) = pk.q;
  }
}

// ---------------------------------------------------------------------------
// proj v3: one 4096x1024x1024 GEMM per tensor (heads fused on N).
// 128x128 tile, BK=64, 4 waves (2x2, each 64x64), reg-staged prefetch,
// XOR-swizzled bf16 LDS. q,k -> [B,H,S,64] (q pre-scaled); v -> [B,H,64,S].
// grid (8 col, 32 row, 3 z): col-fastest => one WT panel per XCD (L2).
// ---------------------------------------------------------------------------
__global__ __launch_bounds__(256) void proj_kernel(
    const float* __restrict__ Xq, const float* __restrict__ Xk, const float* __restrict__ Xv,
    const u16* __restrict__ WT,
    const float* __restrict__ bq, const float* __restrict__ bk, const float* __restrict__ bv,
    u16* __restrict__ qo, u16* __restrict__ ko, u16* __restrict__ vo)
{
  const int z = blockIdx.z;
  const int col = blockIdx.x;     // n-tile (8)
  const int rowb = blockIdx.y;    // m-tile (32)
  const float* X  = (z == 0) ? Xq : (z == 1) ? Xk : Xv;
  const float* Bb = (z == 0) ? bq : (z == 1) ? bk : bv;   // flat [1024]
  u16* out = (z == 0) ? qo : (z == 1) ? ko : vo;
  const float scale = (z == 0) ? 0.125f : 1.0f;
  const u16* WTz = WT + (size_t)z * D_ * D_ + (size_t)col * 128 * D_;

  const int tid = threadIdx.x;
  const int l = tid & 63, w = tid >> 6;
  const int g = l >> 4, lr = l & 15;
  const int wm = w >> 1, wn = w & 1;

  __shared__ u16 Asm[128 * 64];   // [r][k] swizzled 128B rows
  __shared__ u16 Bsm[128 * 64];   // [n][k] swizzled 128B rows

  // staging geometry (same shape for A and B): sub-row = tid>>3, 16B chunk = tid&7
  const int sr = tid >> 3;              // 0..31
  const int sc8 = (tid & 7) * 8;        // elem offset within 64-k row
  const float* aSrc = X + (size_t)(rowb * 128 + sr) * D_ + sc8;   // + p*32 rows
  const u16*   bSrc = WTz + (size_t)sr * D_ + sc8;                 // + i*32 rows

  float4 aP[8]; uint4 bP[4];

#define LOAD_TILE(k0)                                                          \
  {                                                                            \
    _Pragma("unroll")                                                          \
    for (int p = 0; p < 4; ++p) {                                              \
      const float* s = aSrc + (size_t)p * 32 * D_ + (k0);                      \
      aP[2 * p]     = *(const float4*)s;                                       \
      aP[2 * p + 1] = *(const float4*)(s + 4);                                 \
    }                                                                          \
    _Pragma("unroll")                                                          \
    for (int i = 0; i < 4; ++i)                                                \
      bP[i] = *(const uint4*)(bSrc + (size_t)i * 32 * D_ + (k0));              \
  }

#define WRITE_TILE()                                                           \
  {                                                                            \
    _Pragma("unroll")                                                          \
    for (int p = 0; p < 4; ++p) {                                              \
      const int row = p * 32 + sr;                                             \
      union { u16 u[8]; uint4 q; } pk;                                         \
      pk.u[0] = f2bf(aP[2 * p].x); pk.u[1] = f2bf(aP[2 * p].y);                \
      pk.u[2] = f2bf(aP[2 * p].z); pk.u[3] = f2bf(aP[2 * p].w);                \
      pk.u[4] = f2bf(aP[2 * p + 1].x); pk.u[5] = f2bf(aP[2 * p + 1].y);        \
      pk.u[6] = f2bf(aP[2 * p + 1].z); pk.u[7] = f2bf(aP[2 * p + 1].w);        \
      *(uint4*)((char*)Asm + row * 128 + SWZ(row, sc8 * 2)) = pk.q;            \
    }                                                                          \
    _Pragma("unroll")                                                          \
    for (int i = 0; i < 4; ++i) {                                              \
      const int row = i * 32 + sr;                                             \
      *(uint4*)((char*)Bsm + row * 128 + SWZ(row, sc8 * 2)) = bP[i];           \
    }                                                                          \
  }

  LOAD_TILE(0);
  WRITE_TILE();
  __syncthreads();

  const f32x4 zero = {0.f, 0.f, 0.f, 0.f};
  f32x4 acc[4][4];
  #pragma unroll
  for (int mt = 0; mt < 4; ++mt)
    #pragma unroll
    for (int nt = 0; nt < 4; ++nt) acc[mt][nt] = zero;

  for (int ks = 0; ks < 16; ++ks) {
    if (ks < 15) LOAD_TILE((ks + 1) * 64);

    #pragma unroll
    for (int ksub = 0; ksub < 2; ++ksub) {
      FragU aF[4], bF[4];
      const int cb0 = ksub * 64 + g * 8;
      #pragma unroll
      for (int mt = 0; mt < 4; ++mt) {
        const int row = wm * 64 + mt * 16 + lr;
        const char* base = (const char*)Asm + row * 128;
        aF[mt].d2[0] = *(const uint2*)(base + SWZ(row, cb0));
        aF[mt].d2[1] = *(const uint2*)(base + SWZ(row, cb0 + 32));
      }
      #pragma unroll
      for (int nt = 0; nt < 4; ++nt) {
        const int row = wn * 64 + nt * 16 + lr;
        const char* base = (const char*)Bsm + row * 128;
        bF[nt].d2[0] = *(const uint2*)(base + SWZ(row, cb0));
        bF[nt].d2[1] = *(const uint2*)(base + SWZ(row, cb0 + 32));
      }
      #pragma unroll
      for (int mt = 0; mt < 4; ++mt)
        #pragma unroll
        for (int nt = 0; nt < 4; ++nt)
          acc[mt][nt] = __builtin_amdgcn_mfma_f32_16x16x32_bf16(aF[mt].v, bF[nt].v, acc[mt][nt], 0, 0, 0);
    }

    __syncthreads();
    if (ks < 15) WRITE_TILE();
    __syncthreads();
  }

  // epilogue
  #pragma unroll
  for (int nt = 0; nt < 4; ++nt) {
    const int ng = col * 128 + wn * 64 + nt * 16 + lr;   // global n 0..1023
    const float bias = Bb[ng];
    const int h = ng >> 6, n = ng & 63;
    #pragma unroll
    for (int mt = 0; mt < 4; ++mt) {
      const int R = rowb * 128 + wm * 64 + mt * 16 + g * 4;
      const int b = R >> 11, s0 = R & (S_ - 1);
      if (z < 2) {
        #pragma unroll
        for (int r = 0; r < 4; ++r)
          out[(((size_t)b * H_ + h) * S_ + s0 + r) * HD_ + n] =
              f2bf((acc[mt][nt][r] + bias) * scale);
      } else {
        union { u16 u[4]; uint2 d; } pk;
        #pragma unroll
        for (int r = 0; r < 4; ++r) pk.u[r] = f2bf(acc[mt][nt][r] + bias);
        *(uint2*)(out + (((size_t)b * H_ + h) * HD_ + n) * S_ + s0) = pk.d;
      }
    }
  }
#undef LOAD_TILE
#undef WRITE_TILE
}

// ---------------------------------------------------------------------------
// Flash attention (unchanged from round 2).
// ---------------------------------------------------------------------------
__global__ __launch_bounds__(256, 4) void attn_kernel(
    const u16* __restrict__ q, const u16* __restrict__ k,
    const u16* __restrict__ vt, float* __restrict__ att)
{
  const int bid = blockIdx.x;
  const int xcd = bid & 7;
  const int j = bid >> 3;
  const int qt = j & 31;
  const int bh = ((j >> 5) << 3) | xcd;

  const int tid = threadIdx.x;
  const int l = tid & 63, w = tid >> 6;
  const int g = l >> 4, lr = l & 15;
  const int qbase = qt * 64 + w * 16;

  __shared__ u16 Ksm[64 * 64];
  __shared__ u16 Vsm[64 * 64];
  __shared__ u16 Plds[4][16][72];

  const u16* qrow = q + ((size_t)bh * S_ + qbase + lr) * HD_;
  FragU qf[2];
  #pragma unroll
  for (int dc = 0; dc < 2; ++dc) {
    qf[dc].d2[0] = *(const uint2*)(qrow + dc * 32 + g * 4);
    qf[dc].d2[1] = *(const uint2*)(qrow + dc * 32 + 16 + g * 4);
  }

  const char* kByte = (const char*)(k + (size_t)bh * S_ * HD_);
  const char* vByte = (const char*)(vt + (size_t)bh * HD_ * S_);

  const int lo0 = tid * 16, lo1 = tid * 16 + 4096;
  const int r0 = lo0 >> 7, cb0 = lo0 & 127, s0 = cb0 ^ ((r0 & 7) << 4);
  const int r1 = lo1 >> 7, cb1 = lo1 & 127, s1 = cb1 ^ ((r1 & 7) << 4);

  uint4 kA, kB, vA, vB;
  kA = *(const uint4*)(kByte + (size_t)r0 * 128 + s0);
  kB = *(const uint4*)(kByte + (size_t)r1 * 128 + s1);
  vA = *(const uint4*)(vByte + (size_t)r0 * S_ * 2 + s0);
  vB = *(const uint4*)(vByte + (size_t)r1 * S_ * 2 + s1);
  *(uint4*)((char*)Ksm + lo0) = kA;
  *(uint4*)((char*)Ksm + lo1) = kB;
  *(uint4*)((char*)Vsm + lo0) = vA;
  *(uint4*)((char*)Vsm + lo1) = vB;
  __syncthreads();

  const f32x4 zero = {0.f, 0.f, 0.f, 0.f};
  f32x4 accO[4] = {zero, zero, zero, zero};
  float m_ = -3e38f, l_ = 0.f;

#define KREAD(row, cbase) (*(const uint2*)((const char*)Ksm + (row) * 128 + ((cbase) ^ (((row) & 7) << 4))))
#define VREAD(row, cbase) (*(const uint2*)((const char*)Vsm + (row) * 128 + ((cbase) ^ (((row) & 7) << 4))))

  for (int t0 = 0; t0 < S_; t0 += 64) {
    const bool hasNext = (t0 + 64) < S_;
    if (hasNext) {
      kA = *(const uint4*)(kByte + (size_t)(t0 + 64 + r0) * 128 + s0);
      kB = *(const uint4*)(kByte + (size_t)(t0 + 64 + r1) * 128 + s1);
      vA = *(const uint4*)(vByte + (size_t)r0 * S_ * 2 + (t0 + 64) * 2 + s0);
      vB = *(const uint4*)(vByte + (size_t)r1 * S_ * 2 + (t0 + 64) * 2 + s1);
    }

    f32x4 sc[4] = {zero, zero, zero, zero};
    #pragma unroll
    for (int ct = 0; ct < 4; ++ct) {
      const int trow = ct * 16 + lr;
      #pragma unroll
      for (int dc = 0; dc < 2; ++dc) {
        FragU kf;
        kf.d2[0] = KREAD(trow, dc * 64 + g * 8);
        kf.d2[1] = KREAD(trow, dc * 64 + g * 8 + 32);
        sc[ct] = __builtin_amdgcn_mfma_f32_16x16x32_bf16(kf.v, qf[dc].v, sc[ct], 0, 0, 0);
      }
    }

    float mloc = sc[0][0];
    #pragma unroll
    for (int ct = 0; ct < 4; ++ct)
      #pragma unroll
      for (int r = 0; r < 4; ++r) mloc = fmaxf(mloc, sc[ct][r]);
    mloc = fmaxf(mloc, __shfl_xor(mloc, 16));
    mloc = fmaxf(mloc, __shfl_xor(mloc, 32));
    const float mn = fmaxf(m_, mloc);
    const float al = __expf(m_ - mn);
    m_ = mn;
    float ps = 0.f;
    #pragma unroll
    for (int ct = 0; ct < 4; ++ct)
      #pragma unroll
      for (int r = 0; r < 4; ++r) {
        float p = __expf(sc[ct][r] - mn);
        sc[ct][r] = p;
        ps += p;
      }
    ps += __shfl_xor(ps, 16);
    ps += __shfl_xor(ps, 32);
    l_ = l_ * al + ps;

    #pragma unroll
    for (int ct = 0; ct < 4; ++ct) {
      union { u16 u[4]; uint2 d; } pk;
      #pragma unroll
      for (int r = 0; r < 4; ++r) pk.u[r] = f2bf(sc[ct][r]);
      *(uint2*)(&Plds[w][lr][ct * 16 + g * 4]) = pk.d;
    }
    float alr[4];
    #pragma unroll
    for (int r = 0; r < 4; ++r) alr[r] = __shfl(al, g * 4 + r);
    #pragma unroll
    for (int dt = 0; dt < 4; ++dt)
      #pragma unroll
      for (int r = 0; r < 4; ++r) accO[dt][r] *= alr[r];

    FragU pf[2];
    #pragma unroll
    for (int tc = 0; tc < 2; ++tc) {
      const u16* pr = &Plds[w][lr][tc * 32 + g * 4];
      pf[tc].d2[0] = *(const uint2*)pr;
      pf[tc].d2[1] = *(const uint2*)(pr + 16);
    }

    #pragma unroll
    for (int dt = 0; dt < 4; ++dt) {
      const int drow = dt * 16 + lr;
      #pragma unroll
      for (int tc = 0; tc < 2; ++tc) {
        FragU vf;
        vf.d2[0] = VREAD(drow, tc * 64 + g * 8);
        vf.d2[1] = VREAD(drow, tc * 64 + g * 8 + 32);
        accO[dt] = __builtin_amdgcn_mfma_f32_16x16x32_bf16(pf[tc].v, vf.v, accO[dt], 0, 0, 0);
      }
    }

    __syncthreads();
    if (hasNext) {
      *(uint4*)((char*)Ksm + lo0) = kA;
      *(uint4*)((char*)Ksm + lo1) = kB;
      *(uint4*)((char*)Vsm + lo0) = vA;
      *(uint4*)((char*)Vsm + lo1) = vB;
    }
    __syncthreads();
  }

  const float inv = 1.0f / l_;
  const int b = bh >> 4, h = bh & (H_ - 1);
  #pragma unroll
  for (int r = 0; r < 4; ++r) {
    const float ivr = __shfl(inv, g * 4 + r);
    const int s = qbase + g * 4 + r;
    float* op = att + ((size_t)b * S_ + s) * D_ + h * HD_;
    #pragma unroll
    for (int dt = 0; dt < 4; ++dt) op[dt * 16 + lr] = accO[dt][r] * ivr;
  }
#undef KREAD
#undef VREAD
}

// ---------------------------------------------------------------------------
// LayerNorm over last dim (1024): one block per row.
// ---------------------------------------------------------------------------
__global__ __launch_bounds__(256) void ln_kernel(
    const float* __restrict__ att, const float* __restrict__ gamma,
    const float* __restrict__ beta, float* __restrict__ out)
{
  const int row = blockIdx.x;
  const int tid = threadIdx.x;
  const float4 x = ((const float4*)(att + (size_t)row * D_))[tid];
  float s  = x.x + x.y + x.z + x.w;
  float sq = x.x * x.x + x.y * x.y + x.z * x.z + x.w * x.w;
  #pragma unroll
  for (int j = 1; j < 64; j <<= 1) { s += __shfl_xor(s, j); sq += __shfl_xor(sq, j); }
  __shared__ float ls[4], lq[4];
  const int w = tid >> 6;
  if ((tid & 63) == 0) { ls[w] = s; lq[w] = sq; }
  __syncthreads();
  if (tid == 0) {
    ls[0] = ls[0] + ls[1] + ls[2] + ls[3];
    lq[0] = lq[0] + lq[1] + lq[2] + lq[3];
  }
  __syncthreads();
  const float mean = ls[0] * (1.f / D_);
  const float var  = lq[0] * (1.f / D_) - mean * mean;
  const float rs = rsqrtf(var + 1e-5f);
  const float4 gv = ((const float4*)gamma)[tid];
  const float4 bv = ((const float4*)beta)[tid];
  float4 o;
  o.x = (x.x - mean) * rs * gv.x + bv.x;
  o.y = (x.y - mean) * rs * gv.y + bv.y;
  o.z = (x.z - mean) * rs * gv.z + bv.z;
  o.w = (x.w - mean) * rs * gv.w + bv.w;
  ((float4*)(out + (size_t)row * D_))[tid] = o;
}

extern "C" void kernel_launch(void* const* d_in, const int* in_sizes, int n_in,
                              void* d_out, int out_size, void* d_ws, size_t ws_size,
                              hipStream_t stream) {
  const float* queries = (const float*)d_in[0];
  const float* keys    = (const float*)d_in[1];
  const float* values  = (const float*)d_in[2];
  const float* Wq = (const float*)d_in[3];
  const float* bq = (const float*)d_in[4];
  const float* Wk = (const float*)d_in[5];
  const float* bk = (const float*)d_in[6];
  const float* Wv = (const float*)d_in[7];
  const float* bv = (const float*)d_in[8];
  const float* gamma = (const float*)d_in[9];
  const float* beta  = (const float*)d_in[10];
  float* out = (float*)d_out;

  const size_t PER = (size_t)B_ * H_ * S_ * HD_;   // 4,194,304 elements
  u16* q_ws  = (u16*)d_ws;
  u16* k_ws  = q_ws + PER;
  u16* vt_ws = k_ws + PER;
  // WT (6 MB) aliases the att region (16 MB): WT is dead once proj finishes,
  // attn then overwrites the region. Total ws use stays at 40 MB.
  u16* WT = vt_ws + PER;
  float* att_ws = (float*)(vt_ws + PER);

  prep_kernel<<<dim3(48), 256, 0, stream>>>(Wq, Wk, Wv, WT);
  proj_kernel<<<dim3(8, 32, 3), 256, 0, stream>>>(
      queries, keys, values, WT, bq, bk, bv, q_ws, k_ws, vt_ws);
  attn_kernel<<<dim3(1024), 256, 0, stream>>>(q_ws, k_ws, vt_ws, att_ws);
  ln_kernel<<<dim3(4096), 256, 0, stream>>>(att_ws, gamma, beta, out);
}

// Round 4
// 278.439 us; speedup vs baseline: 1.1325x; 1.1325x over previous
//
#include <hip/hip_runtime.h>

#define B_ 2
#define S_ 2048
#define D_ 1024
#define H_ 16
#define HD_ 64

typedef unsigned short u16;
typedef short bf16x8 __attribute__((ext_vector_type(8)));
typedef float f32x4 __attribute__((ext_vector_type(4)));

union FragU { bf16x8 v; u16 u[8]; uint2 d2[2]; unsigned w[4]; };

__device__ __forceinline__ u16 f2bf(float f) {
  unsigned int x = __builtin_bit_cast(unsigned int, f);
  x += 0x7fffu + ((x >> 16) & 1u);   // round-to-nearest-even
  return (u16)(x >> 16);
}

#define SWZ(row, cb) ((cb) ^ (((row) & 7) << 4))

// ---------------------------------------------------------------------------
// prep: W[z][h][k][n] f32  ->  WT[z][h*64+n][k] bf16   (transpose + convert)
// ---------------------------------------------------------------------------
__global__ __launch_bounds__(256) void prep_kernel(
    const float* __restrict__ Wq, const float* __restrict__ Wk,
    const float* __restrict__ Wv, u16* __restrict__ WT)
{
  const int blk = blockIdx.x;
  const int z = blk >> 4, h = blk & 15;
  const float* src = ((z == 0) ? Wq : (z == 1) ? Wk : Wv) + (size_t)h * D_ * HD_;
  u16* dst = WT + (size_t)z * D_ * D_ + (size_t)h * HD_ * D_;   // [64 n][1024 k]
  const int tid = threadIdx.x;
  const int n = tid & 63, kh = tid >> 6;
  for (int k8 = 0; k8 < 32; ++k8) {
    const int kbase = kh * 256 + k8 * 8;
    union { u16 u[8]; uint4 q; } pk;
    #pragma unroll
    for (int m = 0; m < 8; ++m)
      pk.u[m] = f2bf(src[(size_t)(kbase + m) * HD_ + n]);
    *(uint4*)(dst + (size_t)n * D_ + kbase) = pk.q;
  }
}

// ---------------------------------------------------------------------------
// proj v5: fused-N GEMM per tensor. 64x128 tile, BK=64, 4 waves (2x2, each
// 32x64). grid(x=rowb 64, y=col 8, z=3): rowb fastest => all col-blocks of a
// row-panel on the SAME XCD (id%8 == rowb%8) => X fetched once per panel.
// q pre-scaled by log2(e)/8 (exp2-domain softmax downstream).
// ---------------------------------------------------------------------------
__global__ __launch_bounds__(256) void proj_kernel(
    const float* __restrict__ Xq, const float* __restrict__ Xk, const float* __restrict__ Xv,
    const u16* __restrict__ WT,
    const float* __restrict__ bq, const float* __restrict__ bk, const float* __restrict__ bv,
    u16* __restrict__ qo, u16* __restrict__ ko, u16* __restrict__ vo)
{
  const int z = blockIdx.z;
  const int rowb = blockIdx.x;    // m-tile (64)
  const int col  = blockIdx.y;    // n-tile (8)
  const float* X  = (z == 0) ? Xq : (z == 1) ? Xk : Xv;
  const float* Bb = (z == 0) ? bq : (z == 1) ? bk : bv;
  u16* out = (z == 0) ? qo : (z == 1) ? ko : vo;
  const float scale = (z == 0) ? 0.125f * 1.44269504f : 1.0f;  // fold log2e into q
  const u16* WTz = WT + (size_t)z * D_ * D_ + (size_t)col * 128 * D_;

  const int tid = threadIdx.x;
  const int l = tid & 63, w = tid >> 6;
  const int g = l >> 4, lr = l & 15;
  const int wm = w >> 1, wn = w & 1;

  __shared__ u16 Asm[64 * 64];    // 8 KB, swizzled 128B rows [m][k]
  __shared__ u16 Bsm[128 * 64];   // 16 KB, swizzled 128B rows [n][k]

  // A: 64 rows x 64k f32; 4 thr/row, 16 elem (64B) each
  const int asr = tid >> 2, ac = (tid & 3) * 16;
  const float* aSrc = X + (size_t)(rowb * 64 + asr) * D_ + ac;
  // B: 128 rows x 64k bf16; 2 thr/row, 32 elem (64B) each
  const int bsr = tid >> 1, bc = (tid & 1) * 32;
  const u16* bSrc = WTz + (size_t)bsr * D_ + bc;

  float4 aP[4]; uint4 bP[4];

#define LOAD_TILE(k0)                                                          \
  {                                                                            \
    _Pragma("unroll")                                                          \
    for (int i = 0; i < 4; ++i) aP[i] = *(const float4*)(aSrc + (k0) + i * 4); \
    _Pragma("unroll")                                                          \
    for (int i = 0; i < 4; ++i) bP[i] = *(const uint4*)(bSrc + (k0) + i * 8);  \
  }

#define WRITE_TILE()                                                           \
  {                                                                            \
    union { u16 u[16]; uint4 q[2]; } pk;                                       \
    _Pragma("unroll")                                                          \
    for (int i = 0; i < 4; ++i) {                                              \
      pk.u[4 * i + 0] = f2bf(aP[i].x); pk.u[4 * i + 1] = f2bf(aP[i].y);        \
      pk.u[4 * i + 2] = f2bf(aP[i].z); pk.u[4 * i + 3] = f2bf(aP[i].w);        \
    }                                                                          \
    *(uint4*)((char*)Asm + asr * 128 + SWZ(asr, ac * 2)) = pk.q[0];            \
    *(uint4*)((char*)Asm + asr * 128 + SWZ(asr, ac * 2 + 16)) = pk.q[1];       \
    _Pragma("unroll")                                                          \
    for (int i = 0; i < 4; ++i)                                                \
      *(uint4*)((char*)Bsm + bsr * 128 + SWZ(bsr, bc * 2 + i * 16)) = bP[i];   \
  }

  LOAD_TILE(0);
  WRITE_TILE();
  __syncthreads();

  const f32x4 zero = {0.f, 0.f, 0.f, 0.f};
  f32x4 acc[2][4];
  #pragma unroll
  for (int mt = 0; mt < 2; ++mt)
    #pragma unroll
    for (int nt = 0; nt < 4; ++nt) acc[mt][nt] = zero;

  for (int ks = 0; ks < 16; ++ks) {
    if (ks < 15) LOAD_TILE((ks + 1) * 64);

    #pragma unroll
    for (int ksub = 0; ksub < 2; ++ksub) {
      FragU aF[2], bF[4];
      const int cb0 = ksub * 64 + g * 8;
      #pragma unroll
      for (int mt = 0; mt < 2; ++mt) {
        const int row = wm * 32 + mt * 16 + lr;
        const char* base = (const char*)Asm + row * 128;
        aF[mt].d2[0] = *(const uint2*)(base + SWZ(row, cb0));
        aF[mt].d2[1] = *(const uint2*)(base + SWZ(row, cb0 + 32));
      }
      #pragma unroll
      for (int nt = 0; nt < 4; ++nt) {
        const int row = wn * 64 + nt * 16 + lr;
        const char* base = (const char*)Bsm + row * 128;
        bF[nt].d2[0] = *(const uint2*)(base + SWZ(row, cb0));
        bF[nt].d2[1] = *(const uint2*)(base + SWZ(row, cb0 + 32));
      }
      __builtin_amdgcn_s_setprio(1);
      #pragma unroll
      for (int mt = 0; mt < 2; ++mt)
        #pragma unroll
        for (int nt = 0; nt < 4; ++nt)
          acc[mt][nt] = __builtin_amdgcn_mfma_f32_16x16x32_bf16(aF[mt].v, bF[nt].v, acc[mt][nt], 0, 0, 0);
      __builtin_amdgcn_s_setprio(0);
    }

    __syncthreads();
    if (ks < 15) WRITE_TILE();
    __syncthreads();
  }

  // epilogue
  #pragma unroll
  for (int nt = 0; nt < 4; ++nt) {
    const int ng = col * 128 + wn * 64 + nt * 16 + lr;
    const float bias = Bb[ng];
    const int h = ng >> 6, n = ng & 63;
    #pragma unroll
    for (int mt = 0; mt < 2; ++mt) {
      const int R = rowb * 64 + wm * 32 + mt * 16 + g * 4;
      const int b = R >> 11, s0 = R & (S_ - 1);
      if (z < 2) {
        #pragma unroll
        for (int r = 0; r < 4; ++r)
          out[(((size_t)b * H_ + h) * S_ + s0 + r) * HD_ + n] =
              f2bf((acc[mt][nt][r] + bias) * scale);
      } else {
        union { u16 u[4]; uint2 d; } pk;
        #pragma unroll
        for (int r = 0; r < 4; ++r) pk.u[r] = f2bf(acc[mt][nt][r] + bias);
        *(uint2*)(out + (((size_t)b * H_ + h) * HD_ + n) * S_ + s0) = pk.d;
      }
    }
  }
#undef LOAD_TILE
#undef WRITE_TILE
}

// ---------------------------------------------------------------------------
// Flash attention v4: lane-local P pack (no Plds!), exp2-domain softmax
// (q carries log2e/8), defer-max (THR=8), setprio around MFMA clusters.
// ---------------------------------------------------------------------------
__global__ __launch_bounds__(256, 4) void attn_kernel(
    const u16* __restrict__ q, const u16* __restrict__ k,
    const u16* __restrict__ vt, float* __restrict__ att)
{
  const int bid = blockIdx.x;
  const int xcd = bid & 7;
  const int j = bid >> 3;
  const int qt = j & 31;
  const int bh = ((j >> 5) << 3) | xcd;

  const int tid = threadIdx.x;
  const int l = tid & 63, w = tid >> 6;
  const int g = l >> 4, lr = l & 15;
  const int qbase = qt * 64 + w * 16;

  __shared__ u16 Ksm[64 * 64];   // 8 KB
  __shared__ u16 Vsm[64 * 64];   // 8 KB

  const u16* qrow = q + ((size_t)bh * S_ + qbase + lr) * HD_;
  FragU qf[2];
  #pragma unroll
  for (int dc = 0; dc < 2; ++dc) {
    qf[dc].d2[0] = *(const uint2*)(qrow + dc * 32 + g * 4);
    qf[dc].d2[1] = *(const uint2*)(qrow + dc * 32 + 16 + g * 4);
  }

  const char* kByte = (const char*)(k + (size_t)bh * S_ * HD_);
  const char* vByte = (const char*)(vt + (size_t)bh * HD_ * S_);

  const int lo0 = tid * 16, lo1 = tid * 16 + 4096;
  const int r0 = lo0 >> 7, cb0 = lo0 & 127, s0 = cb0 ^ ((r0 & 7) << 4);
  const int r1 = lo1 >> 7, cb1 = lo1 & 127, s1 = cb1 ^ ((r1 & 7) << 4);

  uint4 kA, kB, vA, vB;
  kA = *(const uint4*)(kByte + (size_t)r0 * 128 + s0);
  kB = *(const uint4*)(kByte + (size_t)r1 * 128 + s1);
  vA = *(const uint4*)(vByte + (size_t)r0 * S_ * 2 + s0);
  vB = *(const uint4*)(vByte + (size_t)r1 * S_ * 2 + s1);
  *(uint4*)((char*)Ksm + lo0) = kA;
  *(uint4*)((char*)Ksm + lo1) = kB;
  *(uint4*)((char*)Vsm + lo0) = vA;
  *(uint4*)((char*)Vsm + lo1) = vB;
  __syncthreads();

  const f32x4 zero = {0.f, 0.f, 0.f, 0.f};
  f32x4 accO[4] = {zero, zero, zero, zero};
  float m_ = -3e38f, l_ = 0.f;   // per-lane: q-row = lr (replicated over g)

#define KREAD(row, cbase) (*(const uint2*)((const char*)Ksm + (row) * 128 + ((cbase) ^ (((row) & 7) << 4))))
#define VREAD(row, cbase) (*(const uint2*)((const char*)Vsm + (row) * 128 + ((cbase) ^ (((row) & 7) << 4))))

  for (int t0 = 0; t0 < S_; t0 += 64) {
    const bool hasNext = (t0 + 64) < S_;
    if (hasNext) {
      kA = *(const uint4*)(kByte + (size_t)(t0 + 64 + r0) * 128 + s0);
      kB = *(const uint4*)(kByte + (size_t)(t0 + 64 + r1) * 128 + s1);
      vA = *(const uint4*)(vByte + (size_t)r0 * S_ * 2 + (t0 + 64) * 2 + s0);
      vB = *(const uint4*)(vByte + (size_t)r1 * S_ * 2 + (t0 + 64) * 2 + s1);
    }

    // ---- scores: sc[ct][r] = S2[t = ct*16 + 4g + r][q = lr] (log2 domain) ----
    f32x4 sc[4] = {zero, zero, zero, zero};
    __builtin_amdgcn_s_setprio(1);
    #pragma unroll
    for (int ct = 0; ct < 4; ++ct) {
      const int trow = ct * 16 + lr;
      #pragma unroll
      for (int dc = 0; dc < 2; ++dc) {
        FragU kf;
        kf.d2[0] = KREAD(trow, dc * 64 + g * 8);
        kf.d2[1] = KREAD(trow, dc * 64 + g * 8 + 32);
        sc[ct] = __builtin_amdgcn_mfma_f32_16x16x32_bf16(kf.v, qf[dc].v, sc[ct], 0, 0, 0);
      }
    }
    __builtin_amdgcn_s_setprio(0);

    // ---- online softmax (exp2 domain), defer-max ----
    float pmax = sc[0][0];
    #pragma unroll
    for (int ct = 0; ct < 4; ++ct)
      #pragma unroll
      for (int r = 0; r < 4; ++r) pmax = fmaxf(pmax, sc[ct][r]);
    pmax = fmaxf(pmax, __shfl_xor(pmax, 16));
    pmax = fmaxf(pmax, __shfl_xor(pmax, 32));
    if (!__all(pmax - m_ <= 8.f)) {
      const float mn = fmaxf(m_, pmax);
      const float al = exp2f(m_ - mn);
      m_ = mn;
      l_ *= al;
      float alr[4];
      #pragma unroll
      for (int r = 0; r < 4; ++r) alr[r] = __shfl(al, g * 4 + r);
      #pragma unroll
      for (int dt = 0; dt < 4; ++dt)
        #pragma unroll
        for (int r = 0; r < 4; ++r) accO[dt][r] *= alr[r];
    }
    float ps = 0.f;
    #pragma unroll
    for (int ct = 0; ct < 4; ++ct)
      #pragma unroll
      for (int r = 0; r < 4; ++r) {
        float p = exp2f(sc[ct][r] - m_);
        sc[ct][r] = p;
        ps += p;
      }
    ps += __shfl_xor(ps, 16);
    ps += __shfl_xor(ps, 32);
    l_ += ps;

    // ---- P pack: PV A-fragment is lane-local (no LDS round-trip) ----
    FragU pf[2];
    #pragma unroll
    for (int tc = 0; tc < 2; ++tc) {
      asm("v_cvt_pk_bf16_f32 %0, %1, %2" : "=v"(pf[tc].w[0]) : "v"(sc[2*tc][0]),   "v"(sc[2*tc][1]));
      asm("v_cvt_pk_bf16_f32 %0, %1, %2" : "=v"(pf[tc].w[1]) : "v"(sc[2*tc][2]),   "v"(sc[2*tc][3]));
      asm("v_cvt_pk_bf16_f32 %0, %1, %2" : "=v"(pf[tc].w[2]) : "v"(sc[2*tc+1][0]), "v"(sc[2*tc+1][1]));
      asm("v_cvt_pk_bf16_f32 %0, %1, %2" : "=v"(pf[tc].w[3]) : "v"(sc[2*tc+1][2]), "v"(sc[2*tc+1][3]));
    }

    // ---- PV: accO[q][d] += P @ V ----
    __builtin_amdgcn_s_setprio(1);
    #pragma unroll
    for (int dt = 0; dt < 4; ++dt) {
      const int drow = dt * 16 + lr;
      #pragma unroll
      for (int tc = 0; tc < 2; ++tc) {
        FragU vf;
        vf.d2[0] = VREAD(drow, tc * 64 + g * 8);
        vf.d2[1] = VREAD(drow, tc * 64 + g * 8 + 32);
        accO[dt] = __builtin_amdgcn_mfma_f32_16x16x32_bf16(pf[tc].v, vf.v, accO[dt], 0, 0, 0);
      }
    }
    __builtin_amdgcn_s_setprio(0);

    __syncthreads();
    if (hasNext) {
      *(uint4*)((char*)Ksm + lo0) = kA;
      *(uint4*)((char*)Ksm + lo1) = kB;
      *(uint4*)((char*)Vsm + lo0) = vA;
      *(uint4*)((char*)Vsm + lo1) = vB;
    }
    __syncthreads();
  }

  const float inv = 1.0f / l_;
  const int b = bh >> 4, h = bh & (H_ - 1);
  #pragma unroll
  for (int r = 0; r < 4; ++r) {
    const float ivr = __shfl(inv, g * 4 + r);
    const int s = qbase + g * 4 + r;
    float* op = att + ((size_t)b * S_ + s) * D_ + h * HD_;
    #pragma unroll
    for (int dt = 0; dt < 4; ++dt) op[dt * 16 + lr] = accO[dt][r] * ivr;
  }
#undef KREAD
#undef VREAD
}

// ---------------------------------------------------------------------------
// LayerNorm over last dim (1024): one block per row.
// ---------------------------------------------------------------------------
__global__ __launch_bounds__(256) void ln_kernel(
    const float* __restrict__ att, const float* __restrict__ gamma,
    const float* __restrict__ beta, float* __restrict__ out)
{
  const int row = blockIdx.x;
  const int tid = threadIdx.x;
  const float4 x = ((const float4*)(att + (size_t)row * D_))[tid];
  float s  = x.x + x.y + x.z + x.w;
  float sq = x.x * x.x + x.y * x.y + x.z * x.z + x.w * x.w;
  #pragma unroll
  for (int j = 1; j < 64; j <<= 1) { s += __shfl_xor(s, j); sq += __shfl_xor(sq, j); }
  __shared__ float ls[4], lq[4];
  const int w = tid >> 6;
  if ((tid & 63) == 0) { ls[w] = s; lq[w] = sq; }
  __syncthreads();
  if (tid == 0) {
    ls[0] = ls[0] + ls[1] + ls[2] + ls[3];
    lq[0] = lq[0] + lq[1] + lq[2] + lq[3];
  }
  __syncthreads();
  const float mean = ls[0] * (1.f / D_);
  const float var  = lq[0] * (1.f / D_) - mean * mean;
  const float rs = rsqrtf(var + 1e-5f);
  const float4 gv = ((const float4*)gamma)[tid];
  const float4 bv = ((const float4*)beta)[tid];
  float4 o;
  o.x = (x.x - mean) * rs * gv.x + bv.x;
  o.y = (x.y - mean) * rs * gv.y + bv.y;
  o.z = (x.z - mean) * rs * gv.z + bv.z;
  o.w = (x.w - mean) * rs * gv.w + bv.w;
  ((float4*)(out + (size_t)row * D_))[tid] = o;
}

extern "C" void kernel_launch(void* const* d_in, const int* in_sizes, int n_in,
                              void* d_out, int out_size, void* d_ws, size_t ws_size,
                              hipStream_t stream) {
  const float* queries = (const float*)d_in[0];
  const float* keys    = (const float*)d_in[1];
  const float* values  = (const float*)d_in[2];
  const float* Wq = (const float*)d_in[3];
  const float* bq = (const float*)d_in[4];
  const float* Wk = (const float*)d_in[5];
  const float* bk = (const float*)d_in[6];
  const float* Wv = (const float*)d_in[7];
  const float* bv = (const float*)d_in[8];
  const float* gamma = (const float*)d_in[9];
  const float* beta  = (const float*)d_in[10];
  float* out = (float*)d_out;

  const size_t PER = (size_t)B_ * H_ * S_ * HD_;
  u16* q_ws  = (u16*)d_ws;
  u16* k_ws  = q_ws + PER;
  u16* vt_ws = k_ws + PER;
  // WT (6 MB) aliases the att region (16 MB): dead before attn writes att.
  u16* WT = vt_ws + PER;
  float* att_ws = (float*)(vt_ws + PER);

  prep_kernel<<<dim3(48), 256, 0, stream>>>(Wq, Wk, Wv, WT);
  proj_kernel<<<dim3(64, 8, 3), 256, 0, stream>>>(
      queries, keys, values, WT, bq, bk, bv, q_ws, k_ws, vt_ws);
  attn_kernel<<<dim3(1024), 256, 0, stream>>>(q_ws, k_ws, vt_ws, att_ws);
  ln_kernel<<<dim3(4096), 256, 0, stream>>>(att_ws, gamma, beta, out);
}

// Round 5
// 195.787 us; speedup vs baseline: 1.6106x; 1.4222x over previous
//
#include <hip/hip_runtime.h>

#define B_ 2
#define S_ 2048
#define D_ 1024
#define H_ 16
#define HD_ 64

typedef unsigned short u16;
typedef short bf16x8 __attribute__((ext_vector_type(8)));
typedef float f32x4 __attribute__((ext_vector_type(4)));

union FragU { bf16x8 v; u16 u[8]; uint2 d2[2]; unsigned w[4]; };

__device__ __forceinline__ u16 f2bf(float f) {
  unsigned int x = __builtin_bit_cast(unsigned int, f);
  x += 0x7fffu + ((x >> 16) & 1u);   // round-to-nearest-even
  return (u16)(x >> 16);
}

// async global -> LDS, 16B per lane. dest = wave-uniform base + lane*16.
__device__ __forceinline__ void g2l(const void* g, void* l) {
  __builtin_amdgcn_global_load_lds(
      (const __attribute__((address_space(1))) unsigned int*)g,
      (__attribute__((address_space(3))) unsigned int*)l, 16, 0, 0);
}

// ---------------------------------------------------------------------------
// prep: W[z][h][k][n] f32 -> WT[z][h*64+n][k] bf16, k fragment-interleaved
// within each 32-k group: col' = ((k&15)>>2)*8 + (k>>4)*4 + (k&3), so one
// 16B LDS chunk = one MFMA B-fragment in register order.
// ---------------------------------------------------------------------------
__global__ __launch_bounds__(256) void prep_kernel(
    const float* __restrict__ Wq, const float* __restrict__ Wk,
    const float* __restrict__ Wv, u16* __restrict__ WT)
{
  const int blk = blockIdx.x;
  const int z = blk >> 4, h = blk & 15;
  const float* src = ((z == 0) ? Wq : (z == 1) ? Wk : Wv) + (size_t)h * D_ * HD_;
  u16* dst = WT + (size_t)z * D_ * D_ + (size_t)h * HD_ * D_;   // [64 n][1024 k']
  const int tid = threadIdx.x;
  const int n = tid & 63, kh = tid >> 6;
  for (int k32 = 0; k32 < 8; ++k32) {
    const int kbase = kh * 256 + k32 * 32;
    union { u16 u[32]; uint4 q[4]; } pk;
    #pragma unroll
    for (int m = 0; m < 32; ++m)
      pk.u[((m & 15) >> 2) * 8 + ((m >> 4) << 2) + (m & 3)] =
          f2bf(src[(size_t)(kbase + m) * HD_ + n]);
    #pragma unroll
    for (int j = 0; j < 4; ++j)
      *(uint4*)(dst + (size_t)n * D_ + kbase + j * 8) = pk.q[j];
  }
}

// ---------------------------------------------------------------------------
// proj v6: fused-N GEMM per tensor. 64x128 tile, BK=64, 4 waves (2x2).
// Both tiles staged via global_load_lds (A as f32, B as interleaved bf16),
// double-buffered LDS, pre-swizzled global sources (XOR (row&7)<<4), one
// barrier per k-step. grid(x=rowb fastest) keeps X panels XCD-local.
// ---------------------------------------------------------------------------
__global__ __launch_bounds__(256) void proj_kernel(
    const float* __restrict__ Xq, const float* __restrict__ Xk, const float* __restrict__ Xv,
    const u16* __restrict__ WT,
    const float* __restrict__ bq, const float* __restrict__ bk, const float* __restrict__ bv,
    u16* __restrict__ qo, u16* __restrict__ ko, u16* __restrict__ vo)
{
  const int z = blockIdx.z;
  const int rowb = blockIdx.x;    // m-tile (64)
  const int col  = blockIdx.y;    // n-tile (8)
  const float* X  = (z == 0) ? Xq : (z == 1) ? Xk : Xv;
  const float* Bb = (z == 0) ? bq : (z == 1) ? bk : bv;
  u16* out = (z == 0) ? qo : (z == 1) ? ko : vo;
  const float scale = (z == 0) ? 0.125f * 1.44269504f : 1.0f;  // log2e folded into q

  const int tid = threadIdx.x;
  const int l = tid & 63, w = tid >> 6;
  const int g = l >> 4, lr = l & 15;
  const int wm = w >> 1, wn = w & 1;

  __shared__ float As_[2][64 * 64];   // 16 KB x2, f32 rows of 256B (swizzled)
  __shared__ u16  Bs_[2][128 * 64];   // 16 KB x2, bf16 rows of 128B (swizzled, interleaved)

  const char* Xb = (const char*)(X + (size_t)rowb * 64 * D_);
  const char* Wb = (const char*)(WT + (size_t)z * D_ * D_ + (size_t)col * 128 * D_);

  // per-issue source offsets (pre-swizzled; k0 added at issue time)
  int aOff[4], bOff[4], ldsOff[4];
  #pragma unroll
  for (int i = 0; i < 4; ++i) {
    const int ar = w * 16 + i * 4 + (l >> 4);
    aOff[i] = ar * 4096 + (((l & 15) * 16) ^ ((ar & 7) << 4));
    const int br = w * 32 + i * 8 + (l >> 3);
    bOff[i] = br * 2048 + (((l & 7) * 16) ^ ((br & 7) << 4));
    ldsOff[i] = (w * 4 + i) * 1024;
  }

#define STAGE(buf, k0)                                                         \
  {                                                                            \
    _Pragma("unroll")                                                          \
    for (int i = 0; i < 4; ++i)                                                \
      g2l(Xb + aOff[i] + (k0) * 4, (char*)As_[buf] + ldsOff[i]);               \
    _Pragma("unroll")                                                          \
    for (int i = 0; i < 4; ++i)                                                \
      g2l(Wb + bOff[i] + (k0) * 2, (char*)Bs_[buf] + ldsOff[i]);               \
  }

  STAGE(0, 0);
  __syncthreads();   // compiler drains vmcnt(0) before barrier

  const f32x4 zero = {0.f, 0.f, 0.f, 0.f};
  f32x4 acc[2][4];
  #pragma unroll
  for (int mt = 0; mt < 2; ++mt)
    #pragma unroll
    for (int nt = 0; nt < 4; ++nt) acc[mt][nt] = zero;

  for (int ks = 0; ks < 16; ++ks) {
    const int cur = ks & 1;
    if (ks < 15) STAGE(cur ^ 1, (ks + 1) * 64);

    const char* Ac = (const char*)As_[cur];
    const char* Bc = (const char*)Bs_[cur];
    #pragma unroll
    for (int ksub = 0; ksub < 2; ++ksub) {
      FragU bF[4];
      #pragma unroll
      for (int nt = 0; nt < 4; ++nt) {
        const int row = wn * 64 + nt * 16 + lr;
        bF[nt].v = *(const bf16x8*)(Bc + row * 128 +
                    ((ksub * 64 + g * 16) ^ ((row & 7) << 4)));
      }
      FragU aF[2];
      #pragma unroll
      for (int mt = 0; mt < 2; ++mt) {
        const int row = wm * 32 + mt * 16 + lr;
        const char* base = Ac + row * 256;
        f32x4 lo = *(const f32x4*)(base + ((ksub * 128 + g * 16) ^ ((row & 7) << 4)));
        f32x4 hi = *(const f32x4*)(base + ((ksub * 128 + 64 + g * 16) ^ ((row & 7) << 4)));
        asm("v_cvt_pk_bf16_f32 %0, %1, %2" : "=v"(aF[mt].w[0]) : "v"(lo[0]), "v"(lo[1]));
        asm("v_cvt_pk_bf16_f32 %0, %1, %2" : "=v"(aF[mt].w[1]) : "v"(lo[2]), "v"(lo[3]));
        asm("v_cvt_pk_bf16_f32 %0, %1, %2" : "=v"(aF[mt].w[2]) : "v"(hi[0]), "v"(hi[1]));
        asm("v_cvt_pk_bf16_f32 %0, %1, %2" : "=v"(aF[mt].w[3]) : "v"(hi[2]), "v"(hi[3]));
      }
      __builtin_amdgcn_s_setprio(1);
      #pragma unroll
      for (int mt = 0; mt < 2; ++mt)
        #pragma unroll
        for (int nt = 0; nt < 4; ++nt)
          acc[mt][nt] = __builtin_amdgcn_mfma_f32_16x16x32_bf16(aF[mt].v, bF[nt].v, acc[mt][nt], 0, 0, 0);
      __builtin_amdgcn_s_setprio(0);
    }
    __syncthreads();   // drains vmcnt (next tile landed) + all reads of cur done
  }

  // epilogue (unchanged; measured 24 MB ideal writes in r2)
  #pragma unroll
  for (int nt = 0; nt < 4; ++nt) {
    const int ng = col * 128 + wn * 64 + nt * 16 + lr;
    const float bias = Bb[ng];
    const int h = ng >> 6, n = ng & 63;
    #pragma unroll
    for (int mt = 0; mt < 2; ++mt) {
      const int R = rowb * 64 + wm * 32 + mt * 16 + g * 4;
      const int b = R >> 11, s0 = R & (S_ - 1);
      if (z < 2) {
        #pragma unroll
        for (int r = 0; r < 4; ++r)
          out[(((size_t)b * H_ + h) * S_ + s0 + r) * HD_ + n] =
              f2bf((acc[mt][nt][r] + bias) * scale);
      } else {
        union { u16 u[4]; uint2 d; } pk;
        #pragma unroll
        for (int r = 0; r < 4; ++r) pk.u[r] = f2bf(acc[mt][nt][r] + bias);
        *(uint2*)(out + (((size_t)b * H_ + h) * HD_ + n) * S_ + s0) = pk.d;
      }
    }
  }
#undef STAGE
}

// ---------------------------------------------------------------------------
// Flash attention v4 (unchanged from round 4).
// ---------------------------------------------------------------------------
__global__ __launch_bounds__(256, 4) void attn_kernel(
    const u16* __restrict__ q, const u16* __restrict__ k,
    const u16* __restrict__ vt, float* __restrict__ att)
{
  const int bid = blockIdx.x;
  const int xcd = bid & 7;
  const int j = bid >> 3;
  const int qt = j & 31;
  const int bh = ((j >> 5) << 3) | xcd;

  const int tid = threadIdx.x;
  const int l = tid & 63, w = tid >> 6;
  const int g = l >> 4, lr = l & 15;
  const int qbase = qt * 64 + w * 16;

  __shared__ u16 Ksm[64 * 64];
  __shared__ u16 Vsm[64 * 64];

  const u16* qrow = q + ((size_t)bh * S_ + qbase + lr) * HD_;
  FragU qf[2];
  #pragma unroll
  for (int dc = 0; dc < 2; ++dc) {
    qf[dc].d2[0] = *(const uint2*)(qrow + dc * 32 + g * 4);
    qf[dc].d2[1] = *(const uint2*)(qrow + dc * 32 + 16 + g * 4);
  }

  const char* kByte = (const char*)(k + (size_t)bh * S_ * HD_);
  const char* vByte = (const char*)(vt + (size_t)bh * HD_ * S_);

  const int lo0 = tid * 16, lo1 = tid * 16 + 4096;
  const int r0 = lo0 >> 7, cb0 = lo0 & 127, s0 = cb0 ^ ((r0 & 7) << 4);
  const int r1 = lo1 >> 7, cb1 = lo1 & 127, s1 = cb1 ^ ((r1 & 7) << 4);

  uint4 kA, kB, vA, vB;
  kA = *(const uint4*)(kByte + (size_t)r0 * 128 + s0);
  kB = *(const uint4*)(kByte + (size_t)r1 * 128 + s1);
  vA = *(const uint4*)(vByte + (size_t)r0 * S_ * 2 + s0);
  vB = *(const uint4*)(vByte + (size_t)r1 * S_ * 2 + s1);
  *(uint4*)((char*)Ksm + lo0) = kA;
  *(uint4*)((char*)Ksm + lo1) = kB;
  *(uint4*)((char*)Vsm + lo0) = vA;
  *(uint4*)((char*)Vsm + lo1) = vB;
  __syncthreads();

  const f32x4 zero = {0.f, 0.f, 0.f, 0.f};
  f32x4 accO[4] = {zero, zero, zero, zero};
  float m_ = -3e38f, l_ = 0.f;

#define KREAD(row, cbase) (*(const uint2*)((const char*)Ksm + (row) * 128 + ((cbase) ^ (((row) & 7) << 4))))
#define VREAD(row, cbase) (*(const uint2*)((const char*)Vsm + (row) * 128 + ((cbase) ^ (((row) & 7) << 4))))

  for (int t0 = 0; t0 < S_; t0 += 64) {
    const bool hasNext = (t0 + 64) < S_;
    if (hasNext) {
      kA = *(const uint4*)(kByte + (size_t)(t0 + 64 + r0) * 128 + s0);
      kB = *(const uint4*)(kByte + (size_t)(t0 + 64 + r1) * 128 + s1);
      vA = *(const uint4*)(vByte + (size_t)r0 * S_ * 2 + (t0 + 64) * 2 + s0);
      vB = *(const uint4*)(vByte + (size_t)r1 * S_ * 2 + (t0 + 64) * 2 + s1);
    }

    f32x4 sc[4] = {zero, zero, zero, zero};
    __builtin_amdgcn_s_setprio(1);
    #pragma unroll
    for (int ct = 0; ct < 4; ++ct) {
      const int trow = ct * 16 + lr;
      #pragma unroll
      for (int dc = 0; dc < 2; ++dc) {
        FragU kf;
        kf.d2[0] = KREAD(trow, dc * 64 + g * 8);
        kf.d2[1] = KREAD(trow, dc * 64 + g * 8 + 32);
        sc[ct] = __builtin_amdgcn_mfma_f32_16x16x32_bf16(kf.v, qf[dc].v, sc[ct], 0, 0, 0);
      }
    }
    __builtin_amdgcn_s_setprio(0);

    float pmax = sc[0][0];
    #pragma unroll
    for (int ct = 0; ct < 4; ++ct)
      #pragma unroll
      for (int r = 0; r < 4; ++r) pmax = fmaxf(pmax, sc[ct][r]);
    pmax = fmaxf(pmax, __shfl_xor(pmax, 16));
    pmax = fmaxf(pmax, __shfl_xor(pmax, 32));
    if (!__all(pmax - m_ <= 8.f)) {
      const float mn = fmaxf(m_, pmax);
      const float al = exp2f(m_ - mn);
      m_ = mn;
      l_ *= al;
      float alr[4];
      #pragma unroll
      for (int r = 0; r < 4; ++r) alr[r] = __shfl(al, g * 4 + r);
      #pragma unroll
      for (int dt = 0; dt < 4; ++dt)
        #pragma unroll
        for (int r = 0; r < 4; ++r) accO[dt][r] *= alr[r];
    }
    float ps = 0.f;
    #pragma unroll
    for (int ct = 0; ct < 4; ++ct)
      #pragma unroll
      for (int r = 0; r < 4; ++r) {
        float p = exp2f(sc[ct][r] - m_);
        sc[ct][r] = p;
        ps += p;
      }
    ps += __shfl_xor(ps, 16);
    ps += __shfl_xor(ps, 32);
    l_ += ps;

    FragU pf[2];
    #pragma unroll
    for (int tc = 0; tc < 2; ++tc) {
      asm("v_cvt_pk_bf16_f32 %0, %1, %2" : "=v"(pf[tc].w[0]) : "v"(sc[2*tc][0]),   "v"(sc[2*tc][1]));
      asm("v_cvt_pk_bf16_f32 %0, %1, %2" : "=v"(pf[tc].w[1]) : "v"(sc[2*tc][2]),   "v"(sc[2*tc][3]));
      asm("v_cvt_pk_bf16_f32 %0, %1, %2" : "=v"(pf[tc].w[2]) : "v"(sc[2*tc+1][0]), "v"(sc[2*tc+1][1]));
      asm("v_cvt_pk_bf16_f32 %0, %1, %2" : "=v"(pf[tc].w[3]) : "v"(sc[2*tc+1][2]), "v"(sc[2*tc+1][3]));
    }

    __builtin_amdgcn_s_setprio(1);
    #pragma unroll
    for (int dt = 0; dt < 4; ++dt) {
      const int drow = dt * 16 + lr;
      #pragma unroll
      for (int tc = 0; tc < 2; ++tc) {
        FragU vf;
        vf.d2[0] = VREAD(drow, tc * 64 + g * 8);
        vf.d2[1] = VREAD(drow, tc * 64 + g * 8 + 32);
        accO[dt] = __builtin_amdgcn_mfma_f32_16x16x32_bf16(pf[tc].v, vf.v, accO[dt], 0, 0, 0);
      }
    }
    __builtin_amdgcn_s_setprio(0);

    __syncthreads();
    if (hasNext) {
      *(uint4*)((char*)Ksm + lo0) = kA;
      *(uint4*)((char*)Ksm + lo1) = kB;
      *(uint4*)((char*)Vsm + lo0) = vA;
      *(uint4*)((char*)Vsm + lo1) = vB;
    }
    __syncthreads();
  }

  const float inv = 1.0f / l_;
  const int b = bh >> 4, h = bh & (H_ - 1);
  #pragma unroll
  for (int r = 0; r < 4; ++r) {
    const float ivr = __shfl(inv, g * 4 + r);
    const int s = qbase + g * 4 + r;
    float* op = att + ((size_t)b * S_ + s) * D_ + h * HD_;
    #pragma unroll
    for (int dt = 0; dt < 4; ++dt) op[dt * 16 + lr] = accO[dt][r] * ivr;
  }
#undef KREAD
#undef VREAD
}

// ---------------------------------------------------------------------------
// LayerNorm over last dim (1024): one block per row.
// ---------------------------------------------------------------------------
__global__ __launch_bounds__(256) void ln_kernel(
    const float* __restrict__ att, const float* __restrict__ gamma,
    const float* __restrict__ beta, float* __restrict__ out)
{
  const int row = blockIdx.x;
  const int tid = threadIdx.x;
  const float4 x = ((const float4*)(att + (size_t)row * D_))[tid];
  float s  = x.x + x.y + x.z + x.w;
  float sq = x.x * x.x + x.y * x.y + x.z * x.z + x.w * x.w;
  #pragma unroll
  for (int j = 1; j < 64; j <<= 1) { s += __shfl_xor(s, j); sq += __shfl_xor(sq, j); }
  __shared__ float ls[4], lq[4];
  const int w = tid >> 6;
  if ((tid & 63) == 0) { ls[w] = s; lq[w] = sq; }
  __syncthreads();
  if (tid == 0) {
    ls[0] = ls[0] + ls[1] + ls[2] + ls[3];
    lq[0] = lq[0] + lq[1] + lq[2] + lq[3];
  }
  __syncthreads();
  const float mean = ls[0] * (1.f / D_);
  const float var  = lq[0] * (1.f / D_) - mean * mean;
  const float rs = rsqrtf(var + 1e-5f);
  const float4 gv = ((const float4*)gamma)[tid];
  const float4 bv = ((const float4*)beta)[tid];
  float4 o;
  o.x = (x.x - mean) * rs * gv.x + bv.x;
  o.y = (x.y - mean) * rs * gv.y + bv.y;
  o.z = (x.z - mean) * rs * gv.z + bv.z;
  o.w = (x.w - mean) * rs * gv.w + bv.w;
  ((float4*)(out + (size_t)row * D_))[tid] = o;
}

extern "C" void kernel_launch(void* const* d_in, const int* in_sizes, int n_in,
                              void* d_out, int out_size, void* d_ws, size_t ws_size,
                              hipStream_t stream) {
  const float* queries = (const float*)d_in[0];
  const float* keys    = (const float*)d_in[1];
  const float* values  = (const float*)d_in[2];
  const float* Wq = (const float*)d_in[3];
  const float* bq = (const float*)d_in[4];
  const float* Wk = (const float*)d_in[5];
  const float* bk = (const float*)d_in[6];
  const float* Wv = (const float*)d_in[7];
  const float* bv = (const float*)d_in[8];
  const float* gamma = (const float*)d_in[9];
  const float* beta  = (const float*)d_in[10];
  float* out = (float*)d_out;

  const size_t PER = (size_t)B_ * H_ * S_ * HD_;
  u16* q_ws  = (u16*)d_ws;
  u16* k_ws  = q_ws + PER;
  u16* vt_ws = k_ws + PER;
  // WT (6 MB) aliases the att region (16 MB): dead before attn writes att.
  u16* WT = vt_ws + PER;
  float* att_ws = (float*)(vt_ws + PER);

  prep_kernel<<<dim3(48), 256, 0, stream>>>(Wq, Wk, Wv, WT);
  proj_kernel<<<dim3(64, 8, 3), 256, 0, stream>>>(
      queries, keys, values, WT, bq, bk, bv, q_ws, k_ws, vt_ws);
  attn_kernel<<<dim3(1024), 256, 0, stream>>>(q_ws, k_ws, vt_ws, att_ws);
  ln_kernel<<<dim3(4096), 256, 0, stream>>>(att_ws, gamma, beta, out);
}

// Round 6
// 183.987 us; speedup vs baseline: 1.7139x; 1.0641x over previous
//
#include <hip/hip_runtime.h>

#define B_ 2
#define S_ 2048
#define D_ 1024
#define H_ 16
#define HD_ 64

typedef unsigned short u16;
typedef short bf16x8 __attribute__((ext_vector_type(8)));
typedef float f32x4 __attribute__((ext_vector_type(4)));

union FragU { bf16x8 v; u16 u[8]; uint2 d2[2]; unsigned w[4]; };

__device__ __forceinline__ u16 f2bf(float f) {
  unsigned int x = __builtin_bit_cast(unsigned int, f);
  x += 0x7fffu + ((x >> 16) & 1u);   // round-to-nearest-even
  return (u16)(x >> 16);
}

// async global -> LDS, 16B per lane. dest = wave-uniform base + lane*16.
__device__ __forceinline__ void g2l(const void* g, void* l) {
  __builtin_amdgcn_global_load_lds(
      (const __attribute__((address_space(1))) unsigned int*)g,
      (__attribute__((address_space(3))) unsigned int*)l, 16, 0, 0);
}

#define MFMA16(a, b, c) __builtin_amdgcn_mfma_f32_16x16x32_bf16(a, b, c, 0, 0, 0)

// ---------------------------------------------------------------------------
// prep: W[z][h][k][n] f32 -> WT[z][h*64+n][k] bf16, k fragment-interleaved
// within each 32-k group (col' = ((k&15)>>2)*8 + ((k>>4)<<2) + (k&3)).
// ---------------------------------------------------------------------------
__global__ __launch_bounds__(256) void prep_kernel(
    const float* __restrict__ Wq, const float* __restrict__ Wk,
    const float* __restrict__ Wv, u16* __restrict__ WT)
{
  const int blk = blockIdx.x;
  const int z = blk >> 4, h = blk & 15;
  const float* src = ((z == 0) ? Wq : (z == 1) ? Wk : Wv) + (size_t)h * D_ * HD_;
  u16* dst = WT + (size_t)z * D_ * D_ + (size_t)h * HD_ * D_;   // [64 n][1024 k']
  const int tid = threadIdx.x;
  const int n = tid & 63, kh = tid >> 6;
  for (int k32 = 0; k32 < 8; ++k32) {
    const int kbase = kh * 256 + k32 * 32;
    union { u16 u[32]; uint4 q[4]; } pk;
    #pragma unroll
    for (int m = 0; m < 32; ++m)
      pk.u[((m & 15) >> 2) * 8 + ((m >> 4) << 2) + (m & 3)] =
          f2bf(src[(size_t)(kbase + m) * HD_ + n]);
    #pragma unroll
    for (int j = 0; j < 4; ++j)
      *(uint4*)(dst + (size_t)n * D_ + kbase + j * 8) = pk.q[j];
  }
}

// ---------------------------------------------------------------------------
// proj v7: fused-N GEMM per tensor (core = v6). Epilogue now writes q/k with
// d fragment-interleaved within 32-d groups, and v^T with the matching
// 4-block t-permutation, so attn reads every MFMA fragment as one b128.
// ---------------------------------------------------------------------------
__global__ __launch_bounds__(256) void proj_kernel(
    const float* __restrict__ Xq, const float* __restrict__ Xk, const float* __restrict__ Xv,
    const u16* __restrict__ WT,
    const float* __restrict__ bq, const float* __restrict__ bk, const float* __restrict__ bv,
    u16* __restrict__ qo, u16* __restrict__ ko, u16* __restrict__ vo)
{
  const int z = blockIdx.z;
  const int rowb = blockIdx.x;    // m-tile (64)  -- fastest => XCD-local X panels
  const int col  = blockIdx.y;    // n-tile (8)
  const float* X  = (z == 0) ? Xq : (z == 1) ? Xk : Xv;
  const float* Bb = (z == 0) ? bq : (z == 1) ? bk : bv;
  u16* out = (z == 0) ? qo : (z == 1) ? ko : vo;
  const float scale = (z == 0) ? 0.125f * 1.44269504f : 1.0f;  // log2e folded into q

  const int tid = threadIdx.x;
  const int l = tid & 63, w = tid >> 6;
  const int g = l >> 4, lr = l & 15;
  const int wm = w >> 1, wn = w & 1;

  __shared__ float As_[2][64 * 64];
  __shared__ u16  Bs_[2][128 * 64];

  const char* Xb = (const char*)(X + (size_t)rowb * 64 * D_);
  const char* Wb = (const char*)(WT + (size_t)z * D_ * D_ + (size_t)col * 128 * D_);

  int aOff[4], bOff[4], ldsOff[4];
  #pragma unroll
  for (int i = 0; i < 4; ++i) {
    const int ar = w * 16 + i * 4 + (l >> 4);
    aOff[i] = ar * 4096 + (((l & 15) * 16) ^ ((ar & 7) << 4));
    const int br = w * 32 + i * 8 + (l >> 3);
    bOff[i] = br * 2048 + (((l & 7) * 16) ^ ((br & 7) << 4));
    ldsOff[i] = (w * 4 + i) * 1024;
  }

#define STAGE(buf, k0)                                                         \
  {                                                                            \
    _Pragma("unroll")                                                          \
    for (int i = 0; i < 4; ++i)                                                \
      g2l(Xb + aOff[i] + (k0) * 4, (char*)As_[buf] + ldsOff[i]);               \
    _Pragma("unroll")                                                          \
    for (int i = 0; i < 4; ++i)                                                \
      g2l(Wb + bOff[i] + (k0) * 2, (char*)Bs_[buf] + ldsOff[i]);               \
  }

  STAGE(0, 0);
  __syncthreads();

  const f32x4 zero = {0.f, 0.f, 0.f, 0.f};
  f32x4 acc[2][4];
  #pragma unroll
  for (int mt = 0; mt < 2; ++mt)
    #pragma unroll
    for (int nt = 0; nt < 4; ++nt) acc[mt][nt] = zero;

  for (int ks = 0; ks < 16; ++ks) {
    const int cur = ks & 1;
    if (ks < 15) STAGE(cur ^ 1, (ks + 1) * 64);

    const char* Ac = (const char*)As_[cur];
    const char* Bc = (const char*)Bs_[cur];
    #pragma unroll
    for (int ksub = 0; ksub < 2; ++ksub) {
      FragU bF[4];
      #pragma unroll
      for (int nt = 0; nt < 4; ++nt) {
        const int row = wn * 64 + nt * 16 + lr;
        bF[nt].v = *(const bf16x8*)(Bc + row * 128 +
                    ((ksub * 64 + g * 16) ^ ((row & 7) << 4)));
      }
      FragU aF[2];
      #pragma unroll
      for (int mt = 0; mt < 2; ++mt) {
        const int row = wm * 32 + mt * 16 + lr;
        const char* base = Ac + row * 256;
        f32x4 lo = *(const f32x4*)(base + ((ksub * 128 + g * 16) ^ ((row & 7) << 4)));
        f32x4 hi = *(const f32x4*)(base + ((ksub * 128 + 64 + g * 16) ^ ((row & 7) << 4)));
        asm("v_cvt_pk_bf16_f32 %0, %1, %2" : "=v"(aF[mt].w[0]) : "v"(lo[0]), "v"(lo[1]));
        asm("v_cvt_pk_bf16_f32 %0, %1, %2" : "=v"(aF[mt].w[1]) : "v"(lo[2]), "v"(lo[3]));
        asm("v_cvt_pk_bf16_f32 %0, %1, %2" : "=v"(aF[mt].w[2]) : "v"(hi[0]), "v"(hi[1]));
        asm("v_cvt_pk_bf16_f32 %0, %1, %2" : "=v"(aF[mt].w[3]) : "v"(hi[2]), "v"(hi[3]));
      }
      __builtin_amdgcn_s_setprio(1);
      #pragma unroll
      for (int mt = 0; mt < 2; ++mt)
        #pragma unroll
        for (int nt = 0; nt < 4; ++nt)
          acc[mt][nt] = MFMA16(aF[mt].v, bF[nt].v, acc[mt][nt]);
      __builtin_amdgcn_s_setprio(0);
    }
    __syncthreads();
  }

  // epilogue: q/k -> d-interleaved [B,H,S,64]; v -> t-block-permuted [B,H,64,S]
  #pragma unroll
  for (int nt = 0; nt < 4; ++nt) {
    const int ng = col * 128 + wn * 64 + nt * 16 + lr;
    const float bias = Bb[ng];
    const int h = ng >> 6, n = ng & 63;
    // d' = (n&32) + ((n&15)>>2)*8 + ((n&16)>>4)*4 + (n&3)
    const int dperm = (n & 32) + ((n & 15) >> 2) * 8 + ((n & 16) >> 4) * 4 + (n & 3);
    #pragma unroll
    for (int mt = 0; mt < 2; ++mt) {
      const int R = rowb * 64 + wm * 32 + mt * 16 + g * 4;
      const int b = R >> 11, s0 = R & (S_ - 1);
      if (z < 2) {
        #pragma unroll
        for (int r = 0; r < 4; ++r)
          out[(((size_t)b * H_ + h) * S_ + s0 + r) * HD_ + dperm] =
              f2bf((acc[mt][nt][r] + bias) * scale);
      } else {
        const int a = (s0 >> 2) & 7;   // 4-elem t-block index within 32-group
        const int s0p = (s0 & ~31) + ((2 * (a & 3) + (a >> 2)) << 2);
        union { u16 u[4]; uint2 d; } pk;
        #pragma unroll
        for (int r = 0; r < 4; ++r) pk.u[r] = f2bf(acc[mt][nt][r] + bias);
        *(uint2*)(out + (((size_t)b * H_ + h) * HD_ + n) * S_ + s0p) = pk.d;
      }
    }
  }
#undef STAGE
}

// ---------------------------------------------------------------------------
// Flash attention v5: 32 q/wave (2 subgroups), 128 q/block, 512 blocks.
// Fragment-interleaved q/k/v layouts => every fragment = one b128.
// Padded 144B LDS rows => one address reg + immediate offsets, no swizzle VALU.
// ---------------------------------------------------------------------------
__global__ __launch_bounds__(256) void attn_kernel(
    const u16* __restrict__ q, const u16* __restrict__ k,
    const u16* __restrict__ vt, float* __restrict__ att)
{
  const int bid = blockIdx.x;
  const int xcd = bid & 7;
  const int j = bid >> 3;
  const int qt = j & 15;                    // 16 q-tiles of 128
  const int bh = ((j >> 4) << 3) | xcd;

  const int tid = threadIdx.x;
  const int l = tid & 63, w = tid >> 6;
  const int g = l >> 4, lr = l & 15;
  const int qbase = qt * 128 + w * 32;

  __shared__ __align__(16) char Ksm[64 * 144];   // [t][128B d-frag + 16B pad]
  __shared__ __align__(16) char Vsm[64 * 144];   // [d][128B t-frag + 16B pad]

  // Q fragments: 2 qg x 2 dc, one b128 each (d-interleaved layout)
  FragU qf[2][2];
  #pragma unroll
  for (int qg = 0; qg < 2; ++qg) {
    const char* qrow = (const char*)(q + ((size_t)bh * S_ + qbase + qg * 16 + lr) * HD_);
    qf[qg][0].v = *(const bf16x8*)(qrow + g * 16);
    qf[qg][1].v = *(const bf16x8*)(qrow + 64 + g * 16);
  }

  const char* kByte = (const char*)(k + (size_t)bh * S_ * HD_);
  const char* vByte = (const char*)(vt + (size_t)bh * HD_ * S_);

  // staging: 2x16B chunks each for K and V per thread; linear global, padded LDS
  const int i0 = tid * 16, i1 = i0 + 4096;
  const int r0 = i0 >> 7, c0 = i0 & 127;
  const int r1 = i1 >> 7, c1 = i1 & 127;
  char* kD0 = Ksm + r0 * 144 + c0;
  char* kD1 = Ksm + r1 * 144 + c1;
  char* vD0 = Vsm + r0 * 144 + c0;
  char* vD1 = Vsm + r1 * 144 + c1;
  const char* kS0 = kByte + i0;                       // + t0*128
  const char* kS1 = kByte + i1;
  const char* vS0 = vByte + (size_t)r0 * (S_ * 2) + c0;   // + t0*2
  const char* vS1 = vByte + (size_t)r1 * (S_ * 2) + c1;

  uint4 kA = *(const uint4*)kS0;
  uint4 kB = *(const uint4*)kS1;
  uint4 vA = *(const uint4*)vS0;
  uint4 vB = *(const uint4*)vS1;
  *(uint4*)kD0 = kA; *(uint4*)kD1 = kB;
  *(uint4*)vD0 = vA; *(uint4*)vD1 = vB;
  __syncthreads();

  const f32x4 zero = {0.f, 0.f, 0.f, 0.f};
  f32x4 accO[2][4] = {{zero, zero, zero, zero}, {zero, zero, zero, zero}};
  float m_[2] = {-3e38f, -3e38f}, l_[2] = {0.f, 0.f};

  const char* kfb = Ksm + lr * 144 + g * 16;   // frag base: all else immediate
  const char* vfb = Vsm + lr * 144 + g * 16;

  for (int t0 = 0; t0 < S_; t0 += 64) {
    const bool hasNext = (t0 + 64) < S_;
    if (hasNext) {
      kA = *(const uint4*)(kS0 + (t0 + 64) * 128);
      kB = *(const uint4*)(kS1 + (t0 + 64) * 128);
      vA = *(const uint4*)(vS0 + (t0 + 64) * 2);
      vB = *(const uint4*)(vS1 + (t0 + 64) * 2);
    }

    // ---- QK^T (swapped): sc[qg][ct][r] = S2[t=ct*16+4g+r][q=lr of qg] ----
    f32x4 sc[2][4] = {{zero, zero, zero, zero}, {zero, zero, zero, zero}};
    __builtin_amdgcn_s_setprio(1);
    #pragma unroll
    for (int ct = 0; ct < 4; ++ct) {
      FragU kf0, kf1;
      kf0.v = *(const bf16x8*)(kfb + ct * 2304);
      kf1.v = *(const bf16x8*)(kfb + ct * 2304 + 64);
      sc[0][ct] = MFMA16(kf0.v, qf[0][0].v, sc[0][ct]);
      sc[0][ct] = MFMA16(kf1.v, qf[0][1].v, sc[0][ct]);
      sc[1][ct] = MFMA16(kf0.v, qf[1][0].v, sc[1][ct]);
      sc[1][ct] = MFMA16(kf1.v, qf[1][1].v, sc[1][ct]);
    }
    __builtin_amdgcn_s_setprio(0);

    // ---- online softmax (exp2 domain), defer-max ----
    float pmax[2];
    #pragma unroll
    for (int qg = 0; qg < 2; ++qg) {
      float mm = sc[qg][0][0];
      #pragma unroll
      for (int ct = 0; ct < 4; ++ct)
        #pragma unroll
        for (int r = 0; r < 4; ++r) mm = fmaxf(mm, sc[qg][ct][r]);
      mm = fmaxf(mm, __shfl_xor(mm, 16));
      mm = fmaxf(mm, __shfl_xor(mm, 32));
      pmax[qg] = mm;
    }
    if (__any((pmax[0] - m_[0] > 8.f) || (pmax[1] - m_[1] > 8.f))) {
      #pragma unroll
      for (int qg = 0; qg < 2; ++qg) {
        const float mn = fmaxf(m_[qg], pmax[qg]);
        const float al = exp2f(m_[qg] - mn);
        m_[qg] = mn;
        l_[qg] *= al;
        float alr[4];
        #pragma unroll
        for (int r = 0; r < 4; ++r) alr[r] = __shfl(al, g * 4 + r);
        #pragma unroll
        for (int dt = 0; dt < 4; ++dt)
          #pragma unroll
          for (int r = 0; r < 4; ++r) accO[qg][dt][r] *= alr[r];
      }
    }
    FragU pf[2][2];
    #pragma unroll
    for (int qg = 0; qg < 2; ++qg) {
      float ps = 0.f;
      #pragma unroll
      for (int ct = 0; ct < 4; ++ct)
        #pragma unroll
        for (int r = 0; r < 4; ++r) {
          float p = exp2f(sc[qg][ct][r] - m_[qg]);
          sc[qg][ct][r] = p;
          ps += p;
        }
      ps += __shfl_xor(ps, 16);
      ps += __shfl_xor(ps, 32);
      l_[qg] += ps;
      #pragma unroll
      for (int tc = 0; tc < 2; ++tc) {
        asm("v_cvt_pk_bf16_f32 %0, %1, %2" : "=v"(pf[qg][tc].w[0]) : "v"(sc[qg][2*tc][0]),   "v"(sc[qg][2*tc][1]));
        asm("v_cvt_pk_bf16_f32 %0, %1, %2" : "=v"(pf[qg][tc].w[1]) : "v"(sc[qg][2*tc][2]),   "v"(sc[qg][2*tc][3]));
        asm("v_cvt_pk_bf16_f32 %0, %1, %2" : "=v"(pf[qg][tc].w[2]) : "v"(sc[qg][2*tc+1][0]), "v"(sc[qg][2*tc+1][1]));
        asm("v_cvt_pk_bf16_f32 %0, %1, %2" : "=v"(pf[qg][tc].w[3]) : "v"(sc[qg][2*tc+1][2]), "v"(sc[qg][2*tc+1][3]));
      }
    }

    // ---- PV: accO[qg][dt] (q=4g+r, d=dt*16+lr); V frags shared across qg ----
    __builtin_amdgcn_s_setprio(1);
    #pragma unroll
    for (int dt = 0; dt < 4; ++dt) {
      FragU vf0, vf1;
      vf0.v = *(const bf16x8*)(vfb + dt * 2304);
      vf1.v = *(const bf16x8*)(vfb + dt * 2304 + 64);
      accO[0][dt] = MFMA16(pf[0][0].v, vf0.v, accO[0][dt]);
      accO[0][dt] = MFMA16(pf[0][1].v, vf1.v, accO[0][dt]);
      accO[1][dt] = MFMA16(pf[1][0].v, vf0.v, accO[1][dt]);
      accO[1][dt] = MFMA16(pf[1][1].v, vf1.v, accO[1][dt]);
    }
    __builtin_amdgcn_s_setprio(0);

    __syncthreads();
    if (hasNext) {
      *(uint4*)kD0 = kA; *(uint4*)kD1 = kB;
      *(uint4*)vD0 = vA; *(uint4*)vD1 = vB;
    }
    __syncthreads();
  }

  // epilogue
  const int b = bh >> 4, h = bh & (H_ - 1);
  #pragma unroll
  for (int qg = 0; qg < 2; ++qg) {
    const float inv = 1.0f / l_[qg];
    #pragma unroll
    for (int r = 0; r < 4; ++r) {
      const float ivr = __shfl(inv, g * 4 + r);
      const int s = qbase + qg * 16 + g * 4 + r;
      float* op = att + ((size_t)b * S_ + s) * D_ + h * HD_;
      #pragma unroll
      for (int dt = 0; dt < 4; ++dt) op[dt * 16 + lr] = accO[qg][dt][r] * ivr;
    }
  }
}

// ---------------------------------------------------------------------------
// LayerNorm over last dim (1024): one block per row.
// ---------------------------------------------------------------------------
__global__ __launch_bounds__(256) void ln_kernel(
    const float* __restrict__ att, const float* __restrict__ gamma,
    const float* __restrict__ beta, float* __restrict__ out)
{
  const int row = blockIdx.x;
  const int tid = threadIdx.x;
  const float4 x = ((const float4*)(att + (size_t)row * D_))[tid];
  float s  = x.x + x.y + x.z + x.w;
  float sq = x.x * x.x + x.y * x.y + x.z * x.z + x.w * x.w;
  #pragma unroll
  for (int j = 1; j < 64; j <<= 1) { s += __shfl_xor(s, j); sq += __shfl_xor(sq, j); }
  __shared__ float ls[4], lq[4];
  const int w = tid >> 6;
  if ((tid & 63) == 0) { ls[w] = s; lq[w] = sq; }
  __syncthreads();
  if (tid == 0) {
    ls[0] = ls[0] + ls[1] + ls[2] + ls[3];
    lq[0] = lq[0] + lq[1] + lq[2] + lq[3];
  }
  __syncthreads();
  const float mean = ls[0] * (1.f / D_);
  const float var  = lq[0] * (1.f / D_) - mean * mean;
  const float rs = rsqrtf(var + 1e-5f);
  const float4 gv = ((const float4*)gamma)[tid];
  const float4 bv = ((const float4*)beta)[tid];
  float4 o;
  o.x = (x.x - mean) * rs * gv.x + bv.x;
  o.y = (x.y - mean) * rs * gv.y + bv.y;
  o.z = (x.z - mean) * rs * gv.z + bv.z;
  o.w = (x.w - mean) * rs * gv.w + bv.w;
  ((float4*)(out + (size_t)row * D_))[tid] = o;
}

extern "C" void kernel_launch(void* const* d_in, const int* in_sizes, int n_in,
                              void* d_out, int out_size, void* d_ws, size_t ws_size,
                              hipStream_t stream) {
  const float* queries = (const float*)d_in[0];
  const float* keys    = (const float*)d_in[1];
  const float* values  = (const float*)d_in[2];
  const float* Wq = (const float*)d_in[3];
  const float* bq = (const float*)d_in[4];
  const float* Wk = (const float*)d_in[5];
  const float* bk = (const float*)d_in[6];
  const float* Wv = (const float*)d_in[7];
  const float* bv = (const float*)d_in[8];
  const float* gamma = (const float*)d_in[9];
  const float* beta  = (const float*)d_in[10];
  float* out = (float*)d_out;

  const size_t PER = (size_t)B_ * H_ * S_ * HD_;
  u16* q_ws  = (u16*)d_ws;
  u16* k_ws  = q_ws + PER;
  u16* vt_ws = k_ws + PER;
  // WT (6 MB) aliases the att region (16 MB): dead before attn writes att.
  u16* WT = vt_ws + PER;
  float* att_ws = (float*)(vt_ws + PER);

  prep_kernel<<<dim3(48), 256, 0, stream>>>(Wq, Wk, Wv, WT);
  proj_kernel<<<dim3(64, 8, 3), 256, 0, stream>>>(
      queries, keys, values, WT, bq, bk, bv, q_ws, k_ws, vt_ws);
  attn_kernel<<<dim3(512), 256, 0, stream>>>(q_ws, k_ws, vt_ws, att_ws);
  ln_kernel<<<dim3(4096), 256, 0, stream>>>(att_ws, gamma, beta, out);
}